// Round 12
// baseline (243.220 us; speedup 1.0000x reference)
//
#include <hip/hip_runtime.h>

// ---------------------------------------------------------------------------
// 2-layer GCN forward:  out = A_norm * relu(A_norm * (x@W1) + b1) @ W2 + b2
// A_norm = D^-1/2 (A+I) D^-1/2, applied as dinv[dst] * sum( dinv[src]*m[src] )
// m bf16 row-major [n][128], dinv[src] pre-folded (halves gather traffic).
// agg (R4 structure): wave = 1 dst row, 64-lane coalesced 256B gathers,
// NOW 32-deep gather pipeline (was 16) to raise per-wave MLP.
// CSR build fused: bucketA -> bscan -> bucket_build (LDS-staged, one pass).
// GEMM: MFMA split-bf16, B-fragments register-resident per wave.
// ---------------------------------------------------------------------------

#define RB    9
#define RANGE 512
#define CAPB  16384
#define CHUNK 8192

typedef __attribute__((ext_vector_type(8))) short bf16x8;
typedef __attribute__((ext_vector_type(4))) float f32x4;

__device__ inline float bf_lo(unsigned w) { return __uint_as_float(w << 16); }
__device__ inline float bf_hi(unsigned w) { return __uint_as_float(w & 0xffff0000u); }
__device__ inline unsigned bf16pair(float lo, float hi) {  // RNE pack
    unsigned a = __float_as_uint(lo), b = __float_as_uint(hi);
    a += 0x7fffu + ((a >> 16) & 1u);
    b += 0x7fffu + ((b >> 16) & 1u);
    return (a >> 16) | (b & 0xffff0000u);
}
__device__ inline unsigned short bf16rne(float f) {
    unsigned u = __float_as_uint(f);
    u += 0x7fffu + ((u >> 16) & 1u);
    return (unsigned short)(u >> 16);
}
__device__ inline float bf2f(unsigned short h) { return __uint_as_float(((unsigned)h) << 16); }

__device__ inline void pack_one(int idx, const float* __restrict__ W,
                                uint4* __restrict__ Bhi, uint4* __restrict__ Blo) {
    int lane = idx & 63, ks = (idx >> 6) & 3, nt = idx >> 8;
    int j = nt * 16 + (lane & 15);
    int k0 = ks * 32 + ((lane >> 4) & 3) * 8;
    unsigned hi[4], lo[4];
#pragma unroll
    for (int p = 0; p < 4; p++) {
        float w0 = W[(size_t)(k0 + 2 * p) * 128 + j];
        float w1 = W[(size_t)(k0 + 2 * p + 1) * 128 + j];
        unsigned short h0 = bf16rne(w0), h1 = bf16rne(w1);
        unsigned short l0 = bf16rne(w0 - bf2f(h0)), l1 = bf16rne(w1 - bf2f(h1));
        hi[p] = (unsigned)h0 | ((unsigned)h1 << 16);
        lo[p] = (unsigned)l0 | ((unsigned)l1 << 16);
    }
    Bhi[idx] = make_uint4(hi[0], hi[1], hi[2], hi[3]);
    Blo[idx] = make_uint4(lo[0], lo[1], lo[2], lo[3]);
}

// --- fused setup: detect dtype | init gcur | pack W1,W2 --------------------
__global__ __launch_bounds__(256) void setup(const unsigned* __restrict__ ei, int E,
                                             int* __restrict__ flag,
                                             unsigned* __restrict__ gcur, int NB,
                                             const float* __restrict__ W1,
                                             uint4* __restrict__ Bhi1, uint4* __restrict__ Blo1,
                                             const float* __restrict__ W2,
                                             uint4* __restrict__ Bhi2, uint4* __restrict__ Blo2) {
    const int b = blockIdx.x, t = threadIdx.x;
    if (b == 0) {
        __shared__ int nz;
        if (t == 0) nz = 0;
        __syncthreads();
        int samples = E < 2048 ? E : 2048;
        int cnt = 0;
        for (int i = t; i < samples; i += 256)
            if (ei[2 * i + 1] != 0u) cnt++;
        if (cnt) atomicAdd(&nz, cnt);
        __syncthreads();
        if (t == 0) *flag = (nz == 0) ? 1 : 0;  // all high words zero -> int64
    } else if (b <= 2) {
        int i = (b - 1) * 256 + t;
        if (i < NB) gcur[i] = (unsigned)i * CAPB;
    } else if (b <= 10) {
        pack_one((b - 3) * 256 + t, W1, Bhi1, Blo1);
    } else {
        pack_one((b - 11) * 256 + t, W2, Bhi2, Blo2);
    }
}

// --- phase A: edges -> per-bucket record arrays (4B records) ---------------
__global__ __launch_bounds__(256) void bucketA(const unsigned* __restrict__ ei, int E, int n,
                                               const int* __restrict__ flag,
                                               unsigned* __restrict__ gcur,
                                               unsigned* __restrict__ recs) {
    __shared__ unsigned hist[512];
    __shared__ unsigned offs[512];
    const int t = threadIdx.x;
    const int NB = (n + RANGE - 1) >> RB;
    for (int i = t; i < NB; i += 256) hist[i] = 0u;
    __syncthreads();
    const int base = blockIdx.x * CHUNK;
    const bool i64 = (*flag != 0);
    unsigned rec[32], bk[32];
#pragma unroll
    for (int j = 0; j < 32; j++) {
        int i = base + j * 256 + t;
        unsigned bv = 0xffffffffu, rv = 0u;
        if (i < E) {
            unsigned s, d;
            if (i64) { s = ei[2 * (size_t)i]; d = ei[2 * ((size_t)E + i)]; }
            else     { s = ei[i];             d = ei[(size_t)E + i]; }
            bv = d >> RB;
            rv = (s << RB) | (d & (RANGE - 1));
            atomicAdd(&hist[bv], 1u);
        }
        rec[j] = rv; bk[j] = bv;
    }
    __syncthreads();
    for (int b = t; b < NB; b += 256) {
        unsigned h = hist[b];
        offs[b] = h ? atomicAdd(&gcur[b], h) : 0u;
    }
    __syncthreads();
#pragma unroll
    for (int j = 0; j < 32; j++) {
        unsigned b = bk[j];
        if (b != 0xffffffffu) {
            unsigned pos = atomicAdd(&offs[b], 1u);
            if (pos < (b + 1u) * CAPB) recs[pos] = rec[j];
        }
    }
}

// --- bucket-total exclusive scan (1 wave over NB<=512 buckets) -------------
__global__ void bscan(const unsigned* __restrict__ gcur, unsigned* __restrict__ bbase,
                      int NB, int n) {
    int lane = threadIdx.x;  // 64 threads
    int K = (NB + 63) / 64;
    if (K > 8) K = 8;
    unsigned vals[8];
    unsigned s = 0;
#pragma unroll
    for (int k = 0; k < 8; k++) {
        vals[k] = 0u;
        int b = lane * K + k;
        if (k < K && b < NB) {
            unsigned cnt = gcur[b] - (unsigned)b * CAPB;
            if (cnt > CAPB) cnt = CAPB;
            int valid = n - (b << RB);
            if (valid > RANGE) valid = RANGE;
            if (valid < 0) valid = 0;
            vals[k] = cnt + (unsigned)valid;
        }
        s += vals[k];
    }
    unsigned inc = s;
    for (int o = 1; o < 64; o <<= 1) {
        unsigned u = (unsigned)__shfl_up((int)inc, o, 64);
        if (lane >= o) inc += u;
    }
    unsigned excl = inc - s;
#pragma unroll
    for (int k = 0; k < 8; k++) {
        int b = lane * K + k;
        if (k < K && b < NB) { bbase[b] = excl; excl += vals[k]; }
    }
}

// --- fused CSR build: stage recs in LDS, hist+scan+deg/dinv/row_off+scatter -
__global__ __launch_bounds__(256) void bucket_build(const unsigned* __restrict__ gcur,
                                                    const unsigned* __restrict__ recs,
                                                    const unsigned* __restrict__ bbase,
                                                    unsigned* __restrict__ deg,
                                                    float* __restrict__ dinv,
                                                    int* __restrict__ row_off,
                                                    int* __restrict__ csr, int n) {
    __shared__ unsigned srecs[CAPB];   // 64KB staged records
    __shared__ unsigned hist[RANGE];
    __shared__ unsigned lofs[RANGE];
    __shared__ int cur[RANGE];
    const int b = blockIdx.x, t = threadIdx.x;
    const int node0 = b << RB;
    unsigned base = (unsigned)b * CAPB;
    unsigned cnt = gcur[b] - base; if (cnt > CAPB) cnt = CAPB;
    for (int v = t; v < RANGE; v += 256)
        hist[v] = (node0 + v < n) ? 1u : 0u;   // self-loop
    __syncthreads();
    for (unsigned i = t; i < cnt; i += 256) {
        unsigned r = recs[base + i];
        srecs[i] = r;
        atomicAdd(&hist[r & (RANGE - 1)], 1u);
    }
    __syncthreads();
    if (t < 64) {  // exclusive scan of 512 bins: 64 lanes x 8
        unsigned loc[8], tot = 0;
#pragma unroll
        for (int k = 0; k < 8; k++) { unsigned h = hist[t * 8 + k]; loc[k] = tot; tot += h; }
        unsigned inc = tot;
        for (int o = 1; o < 64; o <<= 1) {
            unsigned u = (unsigned)__shfl_up((int)inc, o, 64);
            if (t >= o) inc += u;
        }
        unsigned excl = inc - tot;
#pragma unroll
        for (int k = 0; k < 8; k++) lofs[t * 8 + k] = excl + loc[k];
    }
    __syncthreads();
    unsigned bb = bbase[b];
    for (int v = t; v < RANGE; v += 256) {
        int node = node0 + v;
        if (node < n) {
            unsigned d = hist[v];
            int ro = (int)(bb + lofs[v]);
            deg[node] = d;
            dinv[node] = rsqrtf((float)d);
            row_off[node] = ro;
            csr[ro] = node;        // self-loop entry
            cur[v] = ro + 1;
        }
    }
    __syncthreads();
    for (unsigned i = t; i < cnt; i += 256) {
        unsigned r = srecs[i];
        int pos = atomicAdd(&cur[r & (RANGE - 1)], 1);
        csr[pos] = (int)(r >> RB);
    }
}

// --- MFMA GEMM: Mout[M,128](bf16) = dinv[r] * (A[M,128] @ W) ----------------
// B register-resident: wave w owns cols [w*32, w*32+32), 4 row-chunks of 16.
template <int SPLIT>
__global__ __launch_bounds__(256) void gemm_mfma(const void* __restrict__ Ain,
                                                 const uint4* __restrict__ Bhi,
                                                 const uint4* __restrict__ Blo,
                                                 const float* __restrict__ dinv,
                                                 unsigned short* __restrict__ Mout, int M) {
    __shared__ unsigned short Ahi[64 * 128];
    __shared__ unsigned short Alo[SPLIT ? 64 * 128 : 64];
    __shared__ unsigned short Cst[16 * 136];  // chunk epilogue staging (pad 8)
    const int t = threadIdx.x;
    const int row0 = blockIdx.x * 64;
    char* ah8 = (char*)Ahi;
    char* al8 = (char*)Alo;

    if (SPLIT) {
        const float4* A4 = (const float4*)Ain;
#pragma unroll
        for (int it = 0; it < 4; it++) {
            int i = it * 256 + t;
            int r = i >> 4, c8 = i & 15;
            int gr = row0 + r;
            float4 v0 = make_float4(0.f, 0.f, 0.f, 0.f), v1 = v0;
            if (gr < M) { v0 = A4[(size_t)gr * 32 + c8 * 2]; v1 = A4[(size_t)gr * 32 + c8 * 2 + 1]; }
            float f[8] = {v0.x, v0.y, v0.z, v0.w, v1.x, v1.y, v1.z, v1.w};
            unsigned hp[4], lp[4];
#pragma unroll
            for (int p = 0; p < 4; p++) {
                unsigned short h0 = bf16rne(f[2 * p]), h1 = bf16rne(f[2 * p + 1]);
                unsigned short l0 = bf16rne(f[2 * p] - bf2f(h0));
                unsigned short l1 = bf16rne(f[2 * p + 1] - bf2f(h1));
                hp[p] = (unsigned)h0 | ((unsigned)h1 << 16);
                lp[p] = (unsigned)l0 | ((unsigned)l1 << 16);
            }
            int byte = (r * 256 + c8 * 16) ^ ((r & 7) << 4);
            *(uint4*)(ah8 + byte) = make_uint4(hp[0], hp[1], hp[2], hp[3]);
            *(uint4*)(al8 + byte) = make_uint4(lp[0], lp[1], lp[2], lp[3]);
        }
    } else {
        const uint4* A4 = (const uint4*)Ain;
#pragma unroll
        for (int it = 0; it < 4; it++) {
            int i = it * 256 + t;
            int r = i >> 4, c8 = i & 15;
            int gr = row0 + r;
            uint4 v = make_uint4(0u, 0u, 0u, 0u);
            if (gr < M) v = A4[(size_t)gr * 16 + c8];
            int byte = (r * 256 + c8 * 16) ^ ((r & 7) << 4);
            *(uint4*)(ah8 + byte) = v;
        }
    }

    const int wv = t >> 6, lane = t & 63;
    const int kh = ((lane >> 4) & 3) * 8;
    const int lr0 = ((lane >> 4) & 3) * 4;   // local row group within chunk
    uint4 bhv[2][4], blv[2][4];
#pragma unroll
    for (int p = 0; p < 2; p++)
#pragma unroll
        for (int ks = 0; ks < 4; ks++) {
            int nt = wv * 2 + p;
            bhv[p][ks] = Bhi[(nt * 4 + ks) * 64 + lane];
            blv[p][ks] = Blo[(nt * 4 + ks) * 64 + lane];
        }
    __syncthreads();   // A staged

#pragma unroll
    for (int c = 0; c < 4; c++) {
        f32x4 acc[2];
        acc[0] = (f32x4){0.f, 0.f, 0.f, 0.f};
        acc[1] = (f32x4){0.f, 0.f, 0.f, 0.f};
        const int arow = c * 16 + (lane & 15);
#pragma unroll
        for (int ks = 0; ks < 4; ks++) {
            int byte = (arow * 256 + (ks * 32 + kh) * 2) ^ ((arow & 7) << 4);
            bf16x8 a_h = *(const bf16x8*)(ah8 + byte);
            bf16x8 a_l;
            if (SPLIT) a_l = *(const bf16x8*)(al8 + byte);
#pragma unroll
            for (int p = 0; p < 2; p++) {
                bf16x8 bh = *(bf16x8*)&bhv[p][ks];
                bf16x8 bl = *(bf16x8*)&blv[p][ks];
                acc[p] = __builtin_amdgcn_mfma_f32_16x16x32_bf16(a_h, bh, acc[p], 0, 0, 0);
                if (SPLIT) acc[p] = __builtin_amdgcn_mfma_f32_16x16x32_bf16(a_l, bh, acc[p], 0, 0, 0);
                acc[p] = __builtin_amdgcn_mfma_f32_16x16x32_bf16(a_h, bl, acc[p], 0, 0, 0);
            }
        }
        float dvr[4];
#pragma unroll
        for (int r = 0; r < 4; r++) {
            int grow = row0 + c * 16 + lr0 + r;
            dvr[r] = (grow < M) ? dinv[grow] : 0.f;
        }
#pragma unroll
        for (int p = 0; p < 2; p++) {
            int nt = wv * 2 + p;
#pragma unroll
            for (int r = 0; r < 4; r++)
                Cst[(lr0 + r) * 136 + nt * 16 + (lane & 15)] = bf16rne(acc[p][r] * dvr[r]);
        }
        __syncthreads();
        {
            int r = t >> 4, c8 = t & 15;
            int gr = row0 + c * 16 + r;
            if (gr < M)
                *(uint4*)(Mout + (size_t)gr * 128 + c8 * 8) = *(uint4*)&Cst[r * 136 + c8 * 8];
        }
        __syncthreads();
    }
}

// --- aggregation (R4 structure, 32-deep gather pipeline) -------------------
__global__ __launch_bounds__(256) void agg_kernel(const unsigned* __restrict__ m,
                                                  const int* __restrict__ csr,
                                                  const int* __restrict__ row_off,
                                                  const unsigned* __restrict__ deg,
                                                  const float* __restrict__ dinv,
                                                  const float* __restrict__ bias,
                                                  void* __restrict__ outp, int n, int mode) {
    int wid = threadIdx.x >> 6, lane = threadIdx.x & 63;
    int v = blockIdx.x * 4 + wid;
    if (v >= n) return;
    int start = row_off[v];
    int cnt = (int)deg[v];
    float ax = 0.f, ay = 0.f;
    int e = 0;
    while (e < cnt) {
        int nload = cnt - e;
        if (nload > 64) nload = 64;
        int sv = 0;
        if (lane < nload) sv = csr[start + e + lane];
        int j = 0;
        for (; j + 32 <= nload; j += 32) {
            unsigned w[32];
#pragma unroll
            for (int q = 0; q < 32; q++) {
                int s = __shfl(sv, j + q);
                w[q] = m[(size_t)s * 64 + lane];
            }
#pragma unroll
            for (int q = 0; q < 32; q++) { ax += bf_lo(w[q]); ay += bf_hi(w[q]); }
        }
        if (j + 16 <= nload) {
            unsigned w[16];
#pragma unroll
            for (int q = 0; q < 16; q++) {
                int s = __shfl(sv, j + q);
                w[q] = m[(size_t)s * 64 + lane];
            }
#pragma unroll
            for (int q = 0; q < 16; q++) { ax += bf_lo(w[q]); ay += bf_hi(w[q]); }
            j += 16;
        }
        if (j + 8 <= nload) {
            unsigned w[8];
#pragma unroll
            for (int q = 0; q < 8; q++) {
                int s = __shfl(sv, j + q);
                w[q] = m[(size_t)s * 64 + lane];
            }
#pragma unroll
            for (int q = 0; q < 8; q++) { ax += bf_lo(w[q]); ay += bf_hi(w[q]); }
            j += 8;
        }
        for (; j < nload; j++) {
            int s = __shfl(sv, j);
            unsigned w = m[(size_t)s * 64 + lane];
            ax += bf_lo(w); ay += bf_hi(w);
        }
        e += nload;
    }
    float dv = dinv[v];
    float2 b = ((const float2*)bias)[lane];
    float ox = fmaf(dv, ax, b.x), oy = fmaf(dv, ay, b.y);
    if (mode) {
        ox = fmaxf(ox, 0.f); oy = fmaxf(oy, 0.f);
        ((unsigned*)outp)[(size_t)v * 64 + lane] = bf16pair(ox, oy);
    } else {
        ((float2*)outp)[(size_t)v * 64 + lane] = make_float2(ox, oy);
    }
}

extern "C" void kernel_launch(void* const* d_in, const int* in_sizes, int n_in,
                              void* d_out, int out_size, void* d_ws, size_t ws_size,
                              hipStream_t stream) {
    const float*    x  = (const float*)d_in[0];
    const float*    W1 = (const float*)d_in[1];
    const float*    b1 = (const float*)d_in[2];
    const float*    W2 = (const float*)d_in[3];
    const float*    b2 = (const float*)d_in[4];
    const unsigned* ei = (const unsigned*)d_in[5];
    int n = in_sizes[0] / 128;
    int E = in_sizes[5] / 2;
    float* out = (float*)d_out;
    int NB = (n + RANGE - 1) >> RB;

    char* w = (char*)d_ws;
    size_t off = 0;
    auto alloc = [&](size_t bytes) -> void* {
        void* p = w + off;
        off = (off + bytes + 255) & ~(size_t)255;
        return p;
    };
    int*            flag     = (int*)alloc(4);
    unsigned*       deg      = (unsigned*)alloc((size_t)n * 4);
    float*          dinv     = (float*)alloc((size_t)n * 4);
    int*            row_off  = (int*)alloc((size_t)(n + 1) * 4);
    unsigned*       bbase    = (unsigned*)alloc(512 * 4);
    unsigned*       gcur     = (unsigned*)alloc(512 * 4);
    uint4*          Bhi1     = (uint4*)alloc(2048 * 16);
    uint4*          Blo1     = (uint4*)alloc(2048 * 16);
    uint4*          Bhi2     = (uint4*)alloc(2048 * 16);
    uint4*          Blo2     = (uint4*)alloc(2048 * 16);
    unsigned*       recs     = (unsigned*)alloc((size_t)NB * CAPB * 4);
    int*            csr      = (int*)alloc((size_t)(E + n + 64) * 4);
    unsigned short* m_bf     = (unsigned short*)alloc((size_t)n * 128 * 2);
    unsigned*       h_bf     = (unsigned*)alloc((size_t)n * 64 * 4);
    (void)ws_size; (void)n_in; (void)out_size;

    int nchunk = (E + CHUNK - 1) / CHUNK;

    hipLaunchKernelGGL(setup, dim3(19), dim3(256), 0, stream,
                       ei, E, flag, gcur, NB, W1, Bhi1, Blo1, W2, Bhi2, Blo2);
    hipLaunchKernelGGL(bucketA, dim3(nchunk), dim3(256), 0, stream, ei, E, n, flag, gcur, recs);
    hipLaunchKernelGGL(bscan, dim3(1), dim3(64), 0, stream, gcur, bbase, NB, n);
    hipLaunchKernelGGL(bucket_build, dim3(NB), dim3(256), 0, stream,
                       gcur, recs, bbase, deg, dinv, row_off, csr, n);

    int gblocks = (n + 63) / 64;
    // layer 1: m = dinv*(x@W1) ; h = bf16(relu(agg(m) + b1))
    hipLaunchKernelGGL((gemm_mfma<1>), dim3(gblocks), dim3(256), 0, stream,
                       (const void*)x, Bhi1, Blo1, dinv, m_bf, n);
    hipLaunchKernelGGL(agg_kernel, dim3((n + 3) / 4), dim3(256), 0, stream,
                       (const unsigned*)m_bf, csr, row_off, deg, dinv, b1, (void*)h_bf, n, 1);
    // layer 2: m = dinv*(h@W2) ; out = agg(m) + b2
    hipLaunchKernelGGL((gemm_mfma<0>), dim3(gblocks), dim3(256), 0, stream,
                       (const void*)h_bf, Bhi2, Blo2, dinv, m_bf, n);
    hipLaunchKernelGGL(agg_kernel, dim3((n + 3) / 4), dim3(256), 0, stream,
                       (const unsigned*)m_bf, csr, row_off, deg, dinv, b2, (void*)out, n, 0);
}

// Round 13
// 222.632 us; speedup vs baseline: 1.0925x; 1.0925x over previous
//
#include <hip/hip_runtime.h>

// ---------------------------------------------------------------------------
// 2-layer GCN forward:  out = A_norm * relu(A_norm * (x@W1) + b1) @ W2 + b2
// A_norm = D^-1/2 (A+I) D^-1/2, applied as dinv[dst] * sum( dinv[src]*m[src] )
// m bf16 row-major [n][128], dinv[src] pre-folded (halves gather traffic).
// agg (R4-proven, FROZEN, 16-deep): wave = 1 dst row, 64-lane coalesced 256B
// gathers. 32-deep tried (R12): -15% via occupancy loss. FINAL form.
// CSR build fused: bucketA -> bscan -> bucket_build (LDS-staged, one pass).
// GEMM: MFMA split-bf16, B-fragments register-resident per wave.
// ---------------------------------------------------------------------------

#define RB    9
#define RANGE 512
#define CAPB  16384
#define CHUNK 8192

typedef __attribute__((ext_vector_type(8))) short bf16x8;
typedef __attribute__((ext_vector_type(4))) float f32x4;

__device__ inline float bf_lo(unsigned w) { return __uint_as_float(w << 16); }
__device__ inline float bf_hi(unsigned w) { return __uint_as_float(w & 0xffff0000u); }
__device__ inline unsigned bf16pair(float lo, float hi) {  // RNE pack
    unsigned a = __float_as_uint(lo), b = __float_as_uint(hi);
    a += 0x7fffu + ((a >> 16) & 1u);
    b += 0x7fffu + ((b >> 16) & 1u);
    return (a >> 16) | (b & 0xffff0000u);
}
__device__ inline unsigned short bf16rne(float f) {
    unsigned u = __float_as_uint(f);
    u += 0x7fffu + ((u >> 16) & 1u);
    return (unsigned short)(u >> 16);
}
__device__ inline float bf2f(unsigned short h) { return __uint_as_float(((unsigned)h) << 16); }

__device__ inline void pack_one(int idx, const float* __restrict__ W,
                                uint4* __restrict__ Bhi, uint4* __restrict__ Blo) {
    int lane = idx & 63, ks = (idx >> 6) & 3, nt = idx >> 8;
    int j = nt * 16 + (lane & 15);
    int k0 = ks * 32 + ((lane >> 4) & 3) * 8;
    unsigned hi[4], lo[4];
#pragma unroll
    for (int p = 0; p < 4; p++) {
        float w0 = W[(size_t)(k0 + 2 * p) * 128 + j];
        float w1 = W[(size_t)(k0 + 2 * p + 1) * 128 + j];
        unsigned short h0 = bf16rne(w0), h1 = bf16rne(w1);
        unsigned short l0 = bf16rne(w0 - bf2f(h0)), l1 = bf16rne(w1 - bf2f(h1));
        hi[p] = (unsigned)h0 | ((unsigned)h1 << 16);
        lo[p] = (unsigned)l0 | ((unsigned)l1 << 16);
    }
    Bhi[idx] = make_uint4(hi[0], hi[1], hi[2], hi[3]);
    Blo[idx] = make_uint4(lo[0], lo[1], lo[2], lo[3]);
}

// --- fused setup: detect dtype | init gcur | pack W1,W2 --------------------
__global__ __launch_bounds__(256) void setup(const unsigned* __restrict__ ei, int E,
                                             int* __restrict__ flag,
                                             unsigned* __restrict__ gcur, int NB,
                                             const float* __restrict__ W1,
                                             uint4* __restrict__ Bhi1, uint4* __restrict__ Blo1,
                                             const float* __restrict__ W2,
                                             uint4* __restrict__ Bhi2, uint4* __restrict__ Blo2) {
    const int b = blockIdx.x, t = threadIdx.x;
    if (b == 0) {
        __shared__ int nz;
        if (t == 0) nz = 0;
        __syncthreads();
        int samples = E < 2048 ? E : 2048;
        int cnt = 0;
        for (int i = t; i < samples; i += 256)
            if (ei[2 * i + 1] != 0u) cnt++;
        if (cnt) atomicAdd(&nz, cnt);
        __syncthreads();
        if (t == 0) *flag = (nz == 0) ? 1 : 0;  // all high words zero -> int64
    } else if (b <= 2) {
        int i = (b - 1) * 256 + t;
        if (i < NB) gcur[i] = (unsigned)i * CAPB;
    } else if (b <= 10) {
        pack_one((b - 3) * 256 + t, W1, Bhi1, Blo1);
    } else {
        pack_one((b - 11) * 256 + t, W2, Bhi2, Blo2);
    }
}

// --- phase A: edges -> per-bucket record arrays (4B records) ---------------
__global__ __launch_bounds__(256) void bucketA(const unsigned* __restrict__ ei, int E, int n,
                                               const int* __restrict__ flag,
                                               unsigned* __restrict__ gcur,
                                               unsigned* __restrict__ recs) {
    __shared__ unsigned hist[512];
    __shared__ unsigned offs[512];
    const int t = threadIdx.x;
    const int NB = (n + RANGE - 1) >> RB;
    for (int i = t; i < NB; i += 256) hist[i] = 0u;
    __syncthreads();
    const int base = blockIdx.x * CHUNK;
    const bool i64 = (*flag != 0);
    unsigned rec[32], bk[32];
#pragma unroll
    for (int j = 0; j < 32; j++) {
        int i = base + j * 256 + t;
        unsigned bv = 0xffffffffu, rv = 0u;
        if (i < E) {
            unsigned s, d;
            if (i64) { s = ei[2 * (size_t)i]; d = ei[2 * ((size_t)E + i)]; }
            else     { s = ei[i];             d = ei[(size_t)E + i]; }
            bv = d >> RB;
            rv = (s << RB) | (d & (RANGE - 1));
            atomicAdd(&hist[bv], 1u);
        }
        rec[j] = rv; bk[j] = bv;
    }
    __syncthreads();
    for (int b = t; b < NB; b += 256) {
        unsigned h = hist[b];
        offs[b] = h ? atomicAdd(&gcur[b], h) : 0u;
    }
    __syncthreads();
#pragma unroll
    for (int j = 0; j < 32; j++) {
        unsigned b = bk[j];
        if (b != 0xffffffffu) {
            unsigned pos = atomicAdd(&offs[b], 1u);
            if (pos < (b + 1u) * CAPB) recs[pos] = rec[j];
        }
    }
}

// --- bucket-total exclusive scan (1 wave over NB<=512 buckets) -------------
__global__ void bscan(const unsigned* __restrict__ gcur, unsigned* __restrict__ bbase,
                      int NB, int n) {
    int lane = threadIdx.x;  // 64 threads
    int K = (NB + 63) / 64;
    if (K > 8) K = 8;
    unsigned vals[8];
    unsigned s = 0;
#pragma unroll
    for (int k = 0; k < 8; k++) {
        vals[k] = 0u;
        int b = lane * K + k;
        if (k < K && b < NB) {
            unsigned cnt = gcur[b] - (unsigned)b * CAPB;
            if (cnt > CAPB) cnt = CAPB;
            int valid = n - (b << RB);
            if (valid > RANGE) valid = RANGE;
            if (valid < 0) valid = 0;
            vals[k] = cnt + (unsigned)valid;
        }
        s += vals[k];
    }
    unsigned inc = s;
    for (int o = 1; o < 64; o <<= 1) {
        unsigned u = (unsigned)__shfl_up((int)inc, o, 64);
        if (lane >= o) inc += u;
    }
    unsigned excl = inc - s;
#pragma unroll
    for (int k = 0; k < 8; k++) {
        int b = lane * K + k;
        if (k < K && b < NB) { bbase[b] = excl; excl += vals[k]; }
    }
}

// --- fused CSR build: stage recs in LDS, hist+scan+deg/dinv/row_off+scatter -
__global__ __launch_bounds__(256) void bucket_build(const unsigned* __restrict__ gcur,
                                                    const unsigned* __restrict__ recs,
                                                    const unsigned* __restrict__ bbase,
                                                    unsigned* __restrict__ deg,
                                                    float* __restrict__ dinv,
                                                    int* __restrict__ row_off,
                                                    int* __restrict__ csr, int n) {
    __shared__ unsigned srecs[CAPB];   // 64KB staged records
    __shared__ unsigned hist[RANGE];
    __shared__ unsigned lofs[RANGE];
    __shared__ int cur[RANGE];
    const int b = blockIdx.x, t = threadIdx.x;
    const int node0 = b << RB;
    unsigned base = (unsigned)b * CAPB;
    unsigned cnt = gcur[b] - base; if (cnt > CAPB) cnt = CAPB;
    for (int v = t; v < RANGE; v += 256)
        hist[v] = (node0 + v < n) ? 1u : 0u;   // self-loop
    __syncthreads();
    for (unsigned i = t; i < cnt; i += 256) {
        unsigned r = recs[base + i];
        srecs[i] = r;
        atomicAdd(&hist[r & (RANGE - 1)], 1u);
    }
    __syncthreads();
    if (t < 64) {  // exclusive scan of 512 bins: 64 lanes x 8
        unsigned loc[8], tot = 0;
#pragma unroll
        for (int k = 0; k < 8; k++) { unsigned h = hist[t * 8 + k]; loc[k] = tot; tot += h; }
        unsigned inc = tot;
        for (int o = 1; o < 64; o <<= 1) {
            unsigned u = (unsigned)__shfl_up((int)inc, o, 64);
            if (t >= o) inc += u;
        }
        unsigned excl = inc - tot;
#pragma unroll
        for (int k = 0; k < 8; k++) lofs[t * 8 + k] = excl + loc[k];
    }
    __syncthreads();
    unsigned bb = bbase[b];
    for (int v = t; v < RANGE; v += 256) {
        int node = node0 + v;
        if (node < n) {
            unsigned d = hist[v];
            int ro = (int)(bb + lofs[v]);
            deg[node] = d;
            dinv[node] = rsqrtf((float)d);
            row_off[node] = ro;
            csr[ro] = node;        // self-loop entry
            cur[v] = ro + 1;
        }
    }
    __syncthreads();
    for (unsigned i = t; i < cnt; i += 256) {
        unsigned r = srecs[i];
        int pos = atomicAdd(&cur[r & (RANGE - 1)], 1);
        csr[pos] = (int)(r >> RB);
    }
}

// --- MFMA GEMM: Mout[M,128](bf16) = dinv[r] * (A[M,128] @ W) ----------------
// B register-resident: wave w owns cols [w*32, w*32+32), 4 row-chunks of 16.
template <int SPLIT>
__global__ __launch_bounds__(256) void gemm_mfma(const void* __restrict__ Ain,
                                                 const uint4* __restrict__ Bhi,
                                                 const uint4* __restrict__ Blo,
                                                 const float* __restrict__ dinv,
                                                 unsigned short* __restrict__ Mout, int M) {
    __shared__ unsigned short Ahi[64 * 128];
    __shared__ unsigned short Alo[SPLIT ? 64 * 128 : 64];
    __shared__ unsigned short Cst[16 * 136];  // chunk epilogue staging (pad 8)
    const int t = threadIdx.x;
    const int row0 = blockIdx.x * 64;
    char* ah8 = (char*)Ahi;
    char* al8 = (char*)Alo;

    if (SPLIT) {
        const float4* A4 = (const float4*)Ain;
#pragma unroll
        for (int it = 0; it < 4; it++) {
            int i = it * 256 + t;
            int r = i >> 4, c8 = i & 15;
            int gr = row0 + r;
            float4 v0 = make_float4(0.f, 0.f, 0.f, 0.f), v1 = v0;
            if (gr < M) { v0 = A4[(size_t)gr * 32 + c8 * 2]; v1 = A4[(size_t)gr * 32 + c8 * 2 + 1]; }
            float f[8] = {v0.x, v0.y, v0.z, v0.w, v1.x, v1.y, v1.z, v1.w};
            unsigned hp[4], lp[4];
#pragma unroll
            for (int p = 0; p < 4; p++) {
                unsigned short h0 = bf16rne(f[2 * p]), h1 = bf16rne(f[2 * p + 1]);
                unsigned short l0 = bf16rne(f[2 * p] - bf2f(h0));
                unsigned short l1 = bf16rne(f[2 * p + 1] - bf2f(h1));
                hp[p] = (unsigned)h0 | ((unsigned)h1 << 16);
                lp[p] = (unsigned)l0 | ((unsigned)l1 << 16);
            }
            int byte = (r * 256 + c8 * 16) ^ ((r & 7) << 4);
            *(uint4*)(ah8 + byte) = make_uint4(hp[0], hp[1], hp[2], hp[3]);
            *(uint4*)(al8 + byte) = make_uint4(lp[0], lp[1], lp[2], lp[3]);
        }
    } else {
        const uint4* A4 = (const uint4*)Ain;
#pragma unroll
        for (int it = 0; it < 4; it++) {
            int i = it * 256 + t;
            int r = i >> 4, c8 = i & 15;
            int gr = row0 + r;
            uint4 v = make_uint4(0u, 0u, 0u, 0u);
            if (gr < M) v = A4[(size_t)gr * 16 + c8];
            int byte = (r * 256 + c8 * 16) ^ ((r & 7) << 4);
            *(uint4*)(ah8 + byte) = v;
        }
    }

    const int wv = t >> 6, lane = t & 63;
    const int kh = ((lane >> 4) & 3) * 8;
    const int lr0 = ((lane >> 4) & 3) * 4;   // local row group within chunk
    uint4 bhv[2][4], blv[2][4];
#pragma unroll
    for (int p = 0; p < 2; p++)
#pragma unroll
        for (int ks = 0; ks < 4; ks++) {
            int nt = wv * 2 + p;
            bhv[p][ks] = Bhi[(nt * 4 + ks) * 64 + lane];
            blv[p][ks] = Blo[(nt * 4 + ks) * 64 + lane];
        }
    __syncthreads();   // A staged

#pragma unroll
    for (int c = 0; c < 4; c++) {
        f32x4 acc[2];
        acc[0] = (f32x4){0.f, 0.f, 0.f, 0.f};
        acc[1] = (f32x4){0.f, 0.f, 0.f, 0.f};
        const int arow = c * 16 + (lane & 15);
#pragma unroll
        for (int ks = 0; ks < 4; ks++) {
            int byte = (arow * 256 + (ks * 32 + kh) * 2) ^ ((arow & 7) << 4);
            bf16x8 a_h = *(const bf16x8*)(ah8 + byte);
            bf16x8 a_l;
            if (SPLIT) a_l = *(const bf16x8*)(al8 + byte);
#pragma unroll
            for (int p = 0; p < 2; p++) {
                bf16x8 bh = *(bf16x8*)&bhv[p][ks];
                bf16x8 bl = *(bf16x8*)&blv[p][ks];
                acc[p] = __builtin_amdgcn_mfma_f32_16x16x32_bf16(a_h, bh, acc[p], 0, 0, 0);
                if (SPLIT) acc[p] = __builtin_amdgcn_mfma_f32_16x16x32_bf16(a_l, bh, acc[p], 0, 0, 0);
                acc[p] = __builtin_amdgcn_mfma_f32_16x16x32_bf16(a_h, bl, acc[p], 0, 0, 0);
            }
        }
        float dvr[4];
#pragma unroll
        for (int r = 0; r < 4; r++) {
            int grow = row0 + c * 16 + lr0 + r;
            dvr[r] = (grow < M) ? dinv[grow] : 0.f;
        }
#pragma unroll
        for (int p = 0; p < 2; p++) {
            int nt = wv * 2 + p;
#pragma unroll
            for (int r = 0; r < 4; r++)
                Cst[(lr0 + r) * 136 + nt * 16 + (lane & 15)] = bf16rne(acc[p][r] * dvr[r]);
        }
        __syncthreads();
        {
            int r = t >> 4, c8 = t & 15;
            int gr = row0 + c * 16 + r;
            if (gr < M)
                *(uint4*)(Mout + (size_t)gr * 128 + c8 * 8) = *(uint4*)&Cst[r * 136 + c8 * 8];
        }
        __syncthreads();
    }
}

// --- aggregation (R4-proven, FROZEN, 16-deep): out[v]=dinv[v]*sum m'[src]+b -
__global__ __launch_bounds__(256) void agg_kernel(const unsigned* __restrict__ m,
                                                  const int* __restrict__ csr,
                                                  const int* __restrict__ row_off,
                                                  const unsigned* __restrict__ deg,
                                                  const float* __restrict__ dinv,
                                                  const float* __restrict__ bias,
                                                  void* __restrict__ outp, int n, int mode) {
    int wid = threadIdx.x >> 6, lane = threadIdx.x & 63;
    int v = blockIdx.x * 4 + wid;
    if (v >= n) return;
    int start = row_off[v];
    int cnt = (int)deg[v];
    float ax = 0.f, ay = 0.f;
    int e = 0;
    while (e < cnt) {
        int nload = cnt - e;
        if (nload > 64) nload = 64;
        int sv = 0;
        if (lane < nload) sv = csr[start + e + lane];
        int j = 0;
        for (; j + 16 <= nload; j += 16) {
            unsigned w[16];
#pragma unroll
            for (int q = 0; q < 16; q++) {
                int s = __shfl(sv, j + q);
                w[q] = m[(size_t)s * 64 + lane];
            }
#pragma unroll
            for (int q = 0; q < 16; q++) { ax += bf_lo(w[q]); ay += bf_hi(w[q]); }
        }
        if (j + 8 <= nload) {
            unsigned w[8];
#pragma unroll
            for (int q = 0; q < 8; q++) {
                int s = __shfl(sv, j + q);
                w[q] = m[(size_t)s * 64 + lane];
            }
#pragma unroll
            for (int q = 0; q < 8; q++) { ax += bf_lo(w[q]); ay += bf_hi(w[q]); }
            j += 8;
        }
        for (; j < nload; j++) {
            int s = __shfl(sv, j);
            unsigned w = m[(size_t)s * 64 + lane];
            ax += bf_lo(w); ay += bf_hi(w);
        }
        e += nload;
    }
    float dv = dinv[v];
    float2 b = ((const float2*)bias)[lane];
    float ox = fmaf(dv, ax, b.x), oy = fmaf(dv, ay, b.y);
    if (mode) {
        ox = fmaxf(ox, 0.f); oy = fmaxf(oy, 0.f);
        ((unsigned*)outp)[(size_t)v * 64 + lane] = bf16pair(ox, oy);
    } else {
        ((float2*)outp)[(size_t)v * 64 + lane] = make_float2(ox, oy);
    }
}

extern "C" void kernel_launch(void* const* d_in, const int* in_sizes, int n_in,
                              void* d_out, int out_size, void* d_ws, size_t ws_size,
                              hipStream_t stream) {
    const float*    x  = (const float*)d_in[0];
    const float*    W1 = (const float*)d_in[1];
    const float*    b1 = (const float*)d_in[2];
    const float*    W2 = (const float*)d_in[3];
    const float*    b2 = (const float*)d_in[4];
    const unsigned* ei = (const unsigned*)d_in[5];
    int n = in_sizes[0] / 128;
    int E = in_sizes[5] / 2;
    float* out = (float*)d_out;
    int NB = (n + RANGE - 1) >> RB;

    char* w = (char*)d_ws;
    size_t off = 0;
    auto alloc = [&](size_t bytes) -> void* {
        void* p = w + off;
        off = (off + bytes + 255) & ~(size_t)255;
        return p;
    };
    int*            flag     = (int*)alloc(4);
    unsigned*       deg      = (unsigned*)alloc((size_t)n * 4);
    float*          dinv     = (float*)alloc((size_t)n * 4);
    int*            row_off  = (int*)alloc((size_t)(n + 1) * 4);
    unsigned*       bbase    = (unsigned*)alloc(512 * 4);
    unsigned*       gcur     = (unsigned*)alloc(512 * 4);
    uint4*          Bhi1     = (uint4*)alloc(2048 * 16);
    uint4*          Blo1     = (uint4*)alloc(2048 * 16);
    uint4*          Bhi2     = (uint4*)alloc(2048 * 16);
    uint4*          Blo2     = (uint4*)alloc(2048 * 16);
    unsigned*       recs     = (unsigned*)alloc((size_t)NB * CAPB * 4);
    int*            csr      = (int*)alloc((size_t)(E + n + 64) * 4);
    unsigned short* m_bf     = (unsigned short*)alloc((size_t)n * 128 * 2);
    unsigned*       h_bf     = (unsigned*)alloc((size_t)n * 64 * 4);
    (void)ws_size; (void)n_in; (void)out_size;

    int nchunk = (E + CHUNK - 1) / CHUNK;

    hipLaunchKernelGGL(setup, dim3(19), dim3(256), 0, stream,
                       ei, E, flag, gcur, NB, W1, Bhi1, Blo1, W2, Bhi2, Blo2);
    hipLaunchKernelGGL(bucketA, dim3(nchunk), dim3(256), 0, stream, ei, E, n, flag, gcur, recs);
    hipLaunchKernelGGL(bscan, dim3(1), dim3(64), 0, stream, gcur, bbase, NB, n);
    hipLaunchKernelGGL(bucket_build, dim3(NB), dim3(256), 0, stream,
                       gcur, recs, bbase, deg, dinv, row_off, csr, n);

    int gblocks = (n + 63) / 64;
    // layer 1: m = dinv*(x@W1) ; h = bf16(relu(agg(m) + b1))
    hipLaunchKernelGGL((gemm_mfma<1>), dim3(gblocks), dim3(256), 0, stream,
                       (const void*)x, Bhi1, Blo1, dinv, m_bf, n);
    hipLaunchKernelGGL(agg_kernel, dim3((n + 3) / 4), dim3(256), 0, stream,
                       (const unsigned*)m_bf, csr, row_off, deg, dinv, b1, (void*)h_bf, n, 1);
    // layer 2: m = dinv*(h@W2) ; out = agg(m) + b2
    hipLaunchKernelGGL((gemm_mfma<0>), dim3(gblocks), dim3(256), 0, stream,
                       (const void*)h_bf, Bhi2, Blo2, dinv, m_bf, n);
    hipLaunchKernelGGL(agg_kernel, dim3((n + 3) / 4), dim3(256), 0, stream,
                       (const unsigned*)m_bf, csr, row_off, deg, dinv, b2, (void*)out, n, 0);
}